// Round 5
// baseline (183.011 us; speedup 1.0000x reference)
//
#include <hip/hip_runtime.h>
#include <hip/hip_bf16.h>
#include <math.h>
#include <stdint.h>

#define N_TOKENS 16384
#define DIM 4096
#define NEXP 64

typedef const __attribute__((address_space(1))) void gvoid_t;
typedef __attribute__((address_space(3))) void svoid_t;
typedef float f32x2 __attribute__((ext_vector_type(2)));

constexpr int MT = 128;  // tokens per block
constexpr int KC = 64;   // k-chunk staged per iteration
constexpr int TM = 4;    // tokens per thread
constexpr int TN = 8;    // experts per thread

#if __has_builtin(__builtin_elementwise_fma)
__device__ __forceinline__ f32x2 fma2(f32x2 a, f32x2 b, f32x2 c) {
  return __builtin_elementwise_fma(a, b, c);  // -> v_pk_fma_f32
}
#else
__device__ __forceinline__ f32x2 fma2(f32x2 a, f32x2 b, f32x2 c) {
  c.x = fmaf(a.x, b.x, c.x);
  c.y = fmaf(a.y, b.y, c.y);
  return c;
}
#endif

// ---------------- K1: logits = x @ W^T (fp32, K-split partials) ----------------
// x: double-buffered LDS via global_load_lds (coalesced, source-XOR-swizzled,
//    linear dest). Stage for chunk t+1 issued BEFORE compute of chunk t; the
//    single end-of-iter barrier (compiler drains vmcnt there) closes the pipe.
// W: NOT staged — 1 MB, L2/L1-resident; each global_load_dwordx4 is
//    wave-broadcast (2 distinct 16B addrs/wave), latency hides under FMAs.
__global__ __launch_bounds__(256, 2) void k1_gemm(const float* __restrict__ x,
                                                  const float* __restrict__ W,
                                                  float* __restrict__ P, int KS) {
  __shared__ float xlds[2][MT * KC];  // 2 x 32 KB
  const int tid = threadIdx.x;
  const int lane = tid & 63;
  const int wid = __builtin_amdgcn_readfirstlane(tid >> 6);  // wave 0..3
  const int tg = tid & 31;  // token slot: tokens tg + 32*i
  const int eg = tid >> 5;  // expert octet 0..7
  const int tok0 = blockIdx.x * MT;
  const int k0 = blockIdx.y * KS;

  const int lr = lane >> 4;     // row within one glds instr (4 rows x 256B)
  const int lslot = lane & 15;  // 16B slot within row
  const int keyt = tg & 15;     // compute-read swizzle key

  f32x2 acc[TM][TN] = {};

  // stage x[tok0..+127][kc..+63] into xlds[b]: 8 glds/wave, 4 rows (1KB) each.
  auto stage = [&](int b, int kc) {
#pragma unroll
    for (int q = 0; q < 8; ++q) {
      const int r0 = 32 * wid + 4 * q;  // wave-uniform row base
      const int r = r0 + lr;
      const float* src =
          x + (size_t)(tok0 + r) * DIM + kc + 4 * (lslot ^ (r & 15));
      float* dst = &xlds[b][r0 * KC];
      __builtin_amdgcn_global_load_lds((gvoid_t*)src, (svoid_t*)dst, 16, 0, 0);
    }
  };

  const int nt = KS / KC;
  stage(0, k0);
  __syncthreads();  // drain prologue stage

  for (int t = 0; t < nt; ++t) {
    const int cur = t & 1;
    if (t + 1 < nt) stage(cur ^ 1, k0 + (t + 1) * KC);  // prefetch next tile

    const int kc = k0 + t * KC;
    const float* wbase = W + (size_t)(eg * TN) * DIM + kc;
    const float* xbase = &xlds[cur][0];

#pragma unroll
    for (int c = 0; c < KC / 4; ++c) {
      f32x2 xa[TM], xb[TM];
#pragma unroll
      for (int i = 0; i < TM; ++i) {
        const float4 t4 =
            *(const float4*)(xbase + (tg + 32 * i) * KC + 4 * (c ^ keyt));
        xa[i].x = t4.x; xa[i].y = t4.y;
        xb[i].x = t4.z; xb[i].y = t4.w;
      }
#pragma unroll
      for (int j = 0; j < TN; ++j) {
        const float4 w = *(const float4*)(wbase + (size_t)j * DIM + 4 * c);
        f32x2 wa, wb;
        wa.x = w.x; wa.y = w.y;
        wb.x = w.z; wb.y = w.w;
#pragma unroll
        for (int i = 0; i < TM; ++i) {
          acc[i][j] = fma2(xa[i], wa, acc[i][j]);
          acc[i][j] = fma2(xb[i], wb, acc[i][j]);
        }
      }
    }
    __syncthreads();  // drains stage glds (vmcnt 0) + closes buf reuse
  }

  // write partial logits: thread covers tokens tg+32i, experts eg*8..+8
#pragma unroll
  for (int i = 0; i < TM; ++i) {
    const int tok = tok0 + tg + 32 * i;
    float* prow = P + ((size_t)blockIdx.y * N_TOKENS + tok) * NEXP + eg * TN;
    float4 o0, o1;
    o0.x = acc[i][0].x + acc[i][0].y;
    o0.y = acc[i][1].x + acc[i][1].y;
    o0.z = acc[i][2].x + acc[i][2].y;
    o0.w = acc[i][3].x + acc[i][3].y;
    o1.x = acc[i][4].x + acc[i][4].y;
    o1.y = acc[i][5].x + acc[i][5].y;
    o1.z = acc[i][6].x + acc[i][6].y;
    o1.w = acc[i][7].x + acc[i][7].y;
    *(float4*)prow = o0;
    *(float4*)(prow + 4) = o1;
  }
}

// ------------- K2: sum partials, softmax, top-2, chunk histograms -------------
__global__ __launch_bounds__(128) void k2_softmax_top2(const float* __restrict__ P,
                                                       int split,
                                                       float* __restrict__ topw,
                                                       int* __restrict__ sel,
                                                       int* __restrict__ cnt) {
  __shared__ int hist[NEXP];
  const int tid = threadIdx.x;
  const int t = blockIdx.x * 128 + tid;
  if (tid < NEXP) hist[tid] = 0;
  __syncthreads();

  float4 v[16];
  {
    const float* row = P + (size_t)t * NEXP;
#pragma unroll
    for (int c = 0; c < 16; ++c) v[c] = *(const float4*)(row + c * 4);
  }
  for (int s = 1; s < split; ++s) {
    const float* row = P + ((size_t)s * N_TOKENS + t) * NEXP;
#pragma unroll
    for (int c = 0; c < 16; ++c) {
      const float4 u = *(const float4*)(row + c * 4);
      v[c].x += u.x; v[c].y += u.y; v[c].z += u.z; v[c].w += u.w;
    }
  }

  float v0 = -INFINITY, v1 = -INFINITY;
  int i0 = 0, i1 = 0;
#define TOP2_STEP(val, idx)                                   \
  {                                                           \
    const float vv = (val);                                   \
    const int ee = (idx);                                     \
    if (vv > v0) { v1 = v0; i1 = i0; v0 = vv; i0 = ee; }      \
    else if (vv > v1) { v1 = vv; i1 = ee; }                   \
  }
#pragma unroll
  for (int c = 0; c < 16; ++c) {
    TOP2_STEP(v[c].x, c * 4 + 0);
    TOP2_STEP(v[c].y, c * 4 + 1);
    TOP2_STEP(v[c].z, c * 4 + 2);
    TOP2_STEP(v[c].w, c * 4 + 3);
  }
#undef TOP2_STEP

  float denom = 0.f;
#pragma unroll
  for (int c = 0; c < 16; ++c) {
    denom += expf(v[c].x - v0);
    denom += expf(v[c].y - v0);
    denom += expf(v[c].z - v0);
    denom += expf(v[c].w - v0);
  }
  const float w0 = 1.0f / denom;           // expf(0) == 1 exactly
  const float w1 = expf(v1 - v0) / denom;

  topw[t * 2 + 0] = w0;
  topw[t * 2 + 1] = w1;
  sel[t * 2 + 0] = i0;
  sel[t * 2 + 1] = i1;
  atomicAdd(&hist[i0], 1);
  atomicAdd(&hist[i1], 1);
  __syncthreads();
  if (tid < NEXP) cnt[blockIdx.x * NEXP + tid] = hist[tid];
}

// -------- K3: expert totals (counts out), exclusive offsets, chunk bases --------
__global__ void k3_scan(const int* __restrict__ cnt, int* __restrict__ cb,
                        float* __restrict__ counts_out) {
  __shared__ int tot[NEXP];
  const int e = threadIdx.x;  // 64 threads
  int run = 0;
  for (int p = 0; p < 128; ++p) run += cnt[p * NEXP + e];
  tot[e] = run;
  counts_out[e] = (float)run;
  __syncthreads();
  int g = 0;
  for (int q = 0; q < e; ++q) g += tot[q];
  int r = g;
  for (int p = 0; p < 128; ++p) {
    cb[p * NEXP + e] = r;
    r += cnt[p * NEXP + e];
  }
}

// ---------------- K4: stable scatter (counting-sort permutation) ----------------
__global__ __launch_bounds__(256) void k4_scatter(const int* __restrict__ sel,
                                                  const int* __restrict__ cb,
                                                  float* __restrict__ gout) {
  __shared__ int wcnt[4 * NEXP];
  const int tid = threadIdx.x;
  const int s = blockIdx.x * 256 + tid;
  const int e = sel[s];
  const int lane = tid & 63;
  const int wv = tid >> 6;
  wcnt[tid] = 0;
  __syncthreads();

  unsigned long long mask = ~0ull;
#pragma unroll
  for (int b = 0; b < 6; ++b) {
    const unsigned long long bb = __ballot((e >> b) & 1);
    mask &= ((e >> b) & 1) ? bb : ~bb;
  }
  const unsigned long long below = mask & ((1ull << lane) - 1ull);
  const int wr = __popcll(below);
  if (wr == 0) wcnt[wv * NEXP + e] = __popcll(mask);
  __syncthreads();

  int base = cb[blockIdx.x * NEXP + e];
  for (int w2 = 0; w2 < wv; ++w2) base += wcnt[w2 * NEXP + e];
  gout[base + wr] = (float)s;
}

extern "C" void kernel_launch(void* const* d_in, const int* in_sizes, int n_in,
                              void* d_out, int out_size, void* d_ws, size_t ws_size,
                              hipStream_t stream) {
  const float* x = (const float*)d_in[0];
  const float* W = (const float*)d_in[1];
  float* out = (float*)d_out;

  auto need = [](int s) {
    return (size_t)s * N_TOKENS * NEXP * 4 + (size_t)N_TOKENS * 2 * 4 +
           2 * (size_t)128 * NEXP * 4;
  };
  int split = 4;  // grid 512 = exactly 2 blocks/CU resident
  if (ws_size < need(4)) split = (ws_size >= need(2)) ? 2 : 1;
  const int KS = DIM / split;

  float* P = (float*)d_ws;
  int* sel = (int*)((char*)d_ws + (size_t)split * N_TOKENS * NEXP * 4);
  int* cnt = sel + N_TOKENS * 2;
  int* cb = cnt + 128 * NEXP;

  hipLaunchKernelGGL(k1_gemm, dim3(N_TOKENS / MT, split), dim3(256), 0, stream,
                     x, W, P, KS);
  hipLaunchKernelGGL(k2_softmax_top2, dim3(N_TOKENS / 128), dim3(128), 0, stream,
                     P, split, out, sel, cnt);
  hipLaunchKernelGGL(k3_scan, dim3(1), dim3(64), 0, stream, cnt, cb,
                     out + 2 * N_TOKENS + 2 * N_TOKENS);
  hipLaunchKernelGGL(k4_scatter, dim3((2 * N_TOKENS) / 256), dim3(256), 0, stream,
                     sel, cb, out + 2 * N_TOKENS);
}